// Round 6
// baseline (514.348 us; speedup 1.0000x reference)
//
#include <hip/hip_runtime.h>

// Greedy NMS: keep[i] = !any(keep[j] for j in knn[i] if j < i)
//
// Round-18: single-variable test of the P-amortization model.
// Model (fits R13/R15/R17): steady-state hop time H = (P + E)/(WCH+1), where
// P ~= 26 us is the phase-1 forced reload of the block's 0.5MB knn slab
// (LLC-latency-limited ~20 GB/s/CU; FETCH_SIZE shows it cache-hits) and
// E ~= 2 us is the detect+probe+fixed-point+publish endgame. R17 measured
// H=5.68 (WCH=4); R15's doubled slab with WCH=2 measured 21 vs predicted 18.
// Change: WCH 4 -> 8 (amortize P over 8 hops; predicted H ~= 3.1 us),
// ECAP 12 -> 16 (window doubles to 16384 rows, lambda ~= 7; overflow
// P(X>16) < 0.1%, fallback rescan kept). Everything else = R17 verbatim
// (spin fixed-point, per-wave immediate publish, s_sleep spin forms).
//
// Output encoding (validated round 4): INT32.
//   d_out[0..M)        : kept flags, 1 / 0
//   d_out[M..M+M*64)   : kept_knn, idx or 150000 (tail doubles as u64 word
//                        scratch, owned by block 73 which never publishes)
// d_ws[0..3]: progress counter (zeroed by init kernel each call)

#define M_ROWS 150000
#define KNN    64
#define BLK    1024
#define QRT    2
#define CHUNK  (BLK * QRT)                        // 2048
#define NCH    ((M_ROWS + CHUNK - 1) / CHUNK)     // 74
#define ICAP   6
#define ECAP   16
#define WCH    8                                  // exl window, chunks (16384 rows)
#define W64PC  (CHUNK / 32)                       // 64 published u64 words/chunk
#define LMW    (((NCH - 1) * CHUNK) / 32)         // 4672 u32 mirror words
#define NBMG   ((NCH - 1) * W64PC)                // 4672 published u64 words
#define OUT_INTS (M_ROWS + M_ROWS * KNN)
#define BMG_INT_OFF (OUT_INTS - NBMG * 2)         // 8B-aligned; rows >= 149854
#define VALIDB (1ull << 32)

__global__ void init_ws_kernel(unsigned int* progress, int* out) {
  const int i = blockIdx.x * blockDim.x + threadIdx.x;
  unsigned long long* bmg64 = (unsigned long long*)(out + BMG_INT_OFF);
  if (i < NBMG) bmg64[i] = 0ull;                  // clear stale valid bits
  if (i == 0) *progress = 0u;
}

// reload a row and probe preds j in [lo, hi) against the LDS bitmask
__device__ __forceinline__ bool probe_reload(const int* __restrict__ rp,
                                             const unsigned int* lm,
                                             int lo, int hi) {
  bool s = false;
#pragma unroll
  for (int u = 0; u < 16; ++u) {
    int4 d = ((const int4*)rp)[u];
    int js[4] = {d.x, d.y, d.z, d.w};
#pragma unroll
    for (int m = 0; m < 4; ++m) {
      int j = js[m];
      if (j >= lo && j < hi && ((lm[j >> 5] >> (j & 31)) & 1u)) s = true;
    }
  }
  return s;
}

__global__ __launch_bounds__(BLK) void nms_chain_kernel(
    const int* __restrict__ knn,
    int* __restrict__ out,
    unsigned int* __restrict__ progress)
{
  const int b    = blockIdx.x;
  const int t    = threadIdx.x;
  const int base = b * CHUNK;
  const int winb = (b > WCH) ? (base - WCH * CHUNK) : 0;   // exl window base

  unsigned long long* bmg64 = (unsigned long long*)(out + BMG_INT_OFF);

  __shared__ unsigned char      st[CHUNK];        // 0 unk, 1 kept, 2 supp
  __shared__ unsigned short     il[ICAP][CHUNK];  // TRANSPOSED: conflict-free
  __shared__ unsigned short     exl[ECAP][CHUNK]; // TRANSPOSED: conflict-free
  __shared__ unsigned int       lm[LMW];          // mirrored keep bits
  __shared__ unsigned int       sh_p;

  int  rowq[QRT];
  bool vq[QRT], ovf[QRT], eovf[QRT], supp[QRT];
  int  ic[QRT], ec[QRT];

#pragma unroll
  for (int q = 0; q < QRT; ++q) {
    rowq[q] = base + q * BLK + t;
    vq[q]   = rowq[q] < M_ROWS;
    ic[q] = ec[q] = 0;
    ovf[q] = eovf[q] = supp[q] = false;
  }

  // ---- classification: intra-chunk + static-window pred lists ----
#pragma unroll
  for (int q = 0; q < QRT; ++q) {
    if (!vq[q]) continue;
    const int o   = q * BLK + t;
    const int row = rowq[q];
    const int* rp = knn + (long long)row * KNN;
#pragma unroll
    for (int u = 0; u < 16; ++u) {
      int4 d = ((const int4*)rp)[u];
      int js[4] = {d.x, d.y, d.z, d.w};
#pragma unroll
      for (int m = 0; m < 4; ++m) {
        int j = js[m];
        if (j < row) {                            // strict <: ref semantics
          if (j >= base) {
            if (ic[q] < ICAP) il[ic[q]][o] = (unsigned short)(j - base);
            ++ic[q];
          } else if (j >= winb) {
            if (ec[q] < ECAP) exl[ec[q]][o] = (unsigned short)(j - winb);
            ++ec[q];
          }
          // j < winb: covered by the phase-1 reload probe
        }
      }
    }
  }
#pragma unroll
  for (int q = 0; q < QRT; ++q) {
    ovf[q]  = ic[q] > ICAP; if (ovf[q])  ic[q] = ICAP;
    eovf[q] = ec[q] > ECAP; if (eovf[q]) ec[q] = ECAP;
  }

  // ---- pre-wait: read il lists back into registers (own writes; no barrier;
  //      full unroll -> compile-time indices -> stays in VGPRs) ----
  unsigned short ilr[QRT][ICAP];
#pragma unroll
  for (int q = 0; q < QRT; ++q)
#pragma unroll
    for (int x = 0; x < ICAP; ++x)
      ilr[q][x] = il[x][q * BLK + t];             // garbage beyond ic[q]: never used

  // ---- wait path ----
  int praw1 = 0, wcop = 0;
  if (b > WCH) {
    // phase 1: counter is only a trigger hint for the single forced reload
    if (t < 64) {
      int pr = 0;
      for (int spin = 0; spin < (1 << 22); ++spin) {
        pr = (int)__hip_atomic_load(progress, __ATOMIC_RELAXED,
                                    __HIP_MEMORY_SCOPE_AGENT);
        if (pr >= b - WCH) break;
        __builtin_amdgcn_s_sleep(2);
      }
      if (t == 0) sh_p = (unsigned int)pr;
    }
    __syncthreads();                              // sh_p visible
    praw1 = (int)sh_p; if (praw1 > b) praw1 = b;
    const int wt = praw1 * W64PC;
    for (int w = t; w < wt; w += BLK) {           // per-word valid-spin backstop
      unsigned long long v = __hip_atomic_load(&bmg64[w], __ATOMIC_RELAXED,
                                               __HIP_MEMORY_SCOPE_AGENT);
      int g1 = 0;
      while (!(v & VALIDB) && ++g1 < (1 << 22)) {
        __builtin_amdgcn_s_sleep(1);
        v = __hip_atomic_load(&bmg64[w], __ATOMIC_RELAXED,
                              __HIP_MEMORY_SCOPE_AGENT);
      }
      lm[w] = (unsigned int)v;
    }
    wcop = wt;
    __syncthreads();                              // lm visible
    const int lim = praw1 * CHUNK;
#pragma unroll
    for (int q = 0; q < QRT; ++q)
      if (vq[q])
        supp[q] = probe_reload(knn + (long long)rowq[q] * KNN, lm, 0, lim);
  }
  // phase 2: turn-wait == data arrival. Spin on predecessor words directly
  // (typically 512 new words -> waves 0-7 spin; others park at the barrier).
  if (b > 0 && wcop < b * W64PC) {
    const int wt = b * W64PC;
    for (int w = wcop + t; w < wt; w += BLK) {
      unsigned long long v = __hip_atomic_load(&bmg64[w], __ATOMIC_RELAXED,
                                               __HIP_MEMORY_SCOPE_AGENT);
      int g2 = 0;
      while (!(v & VALIDB) && ++g2 < (1 << 22)) {
        __builtin_amdgcn_s_sleep(1);
        v = __hip_atomic_load(&bmg64[w], __ATOMIC_RELAXED,
                              __HIP_MEMORY_SCOPE_AGENT);
      }
      lm[w] = (unsigned int)v;
    }
    __syncthreads();                              // lm complete
  }
  if (b > 0) {
    // window probes, unrolled + predicated (no break): loads pipeline
    const int pr1lim = praw1 * CHUNK;
#pragma unroll
    for (int q = 0; q < QRT; ++q) {
      if (!vq[q] || supp[q]) continue;
      const int o = q * BLK + t;
      const int n = ec[q];
      bool s = false;
#pragma unroll
      for (int x = 0; x < ECAP; ++x) {
        if (x < n) {
          int j = winb + (int)exl[x][o];
          s |= (j >= pr1lim) && (((lm[j >> 5] >> (j & 31)) & 1u) != 0u);
        }
      }
      if (s) supp[q] = true;
      if (!supp[q] && eovf[q])                    // dropped entries (rare)
        supp[q] = probe_reload(knn + (long long)rowq[q] * KNN, lm, winb, base);
    }
  }

  // ---- intra-chunk fixed-point: BARRIER-FREE SPIN (validated R17) ----
  // st is monotone (0 -> 1|2, written once, only by the owning thread).
  // Workgroup-scope relaxed atomics pin the LDS loads/stores in the loop.
  unsigned char myst[QRT];
#pragma unroll
  for (int q = 0; q < QRT; ++q) {
    myst[q] = (!vq[q] || supp[q]) ? (unsigned char)2
            : ((ic[q] == 0 && !ovf[q]) ? (unsigned char)1 : (unsigned char)0);
    __hip_atomic_store(&st[q * BLK + t], myst[q],
                       __ATOMIC_RELAXED, __HIP_MEMORY_SCOPE_WORKGROUP);
  }
  __syncthreads();                                // init visible to all waves

  bool undec = (myst[0] == 0) | (myst[1] == 0);
  for (int pass = 0; pass < (1 << 14) && undec; ++pass) {
    undec = false;
#pragma unroll
    for (int q = 0; q < QRT; ++q) {
      if (myst[q] != 0) continue;
      const int o = q * BLK + t;
      bool anyK = false, allD = true;
      if (!ovf[q]) {
#pragma unroll
        for (int x = 0; x < ICAP; ++x) {
          if (x < ic[q]) {
            unsigned char v = __hip_atomic_load(&st[ilr[q][x]],
                __ATOMIC_RELAXED, __HIP_MEMORY_SCOPE_WORKGROUP);
            anyK |= (v == 1); allD &= (v != 0);
          }
        }
      } else {                                    // rare: rescan from global
        const int row = rowq[q];
        const int* rp = knn + (long long)row * KNN;
#pragma unroll
        for (int k = 0; k < KNN; ++k) {
          int j = rp[k];
          if (j >= base && j < row) {
            unsigned char v = __hip_atomic_load(&st[j - base],
                __ATOMIC_RELAXED, __HIP_MEMORY_SCOPE_WORKGROUP);
            anyK |= (v == 1); allD &= (v != 0);
          }
        }
      }
      if (anyK)      myst[q] = 2;
      else if (allD) myst[q] = 1;
      if (myst[q] != 0)
        __hip_atomic_store(&st[o], myst[q],
                           __ATOMIC_RELAXED, __HIP_MEMORY_SCOPE_WORKGROUP);
      else
        undec = true;
    }
  }

  // ---- publish: PER-WAVE, immediate (no block barrier before words) ----
  bool kq[QRT];
#pragma unroll
  for (int q = 0; q < QRT; ++q)
    kq[q] = vq[q] && (myst[q] == 1);

  if (b < NCH - 1) {
    const int lane = t & 63;
#pragma unroll
    for (int q = 0; q < QRT; ++q) {
      unsigned long long ba = __ballot(kq[q]);    // rows base+q*1024+(t&~63)+lane
      const int g = b * W64PC + ((q * BLK + (t & ~63)) >> 5);
      if (lane == 0)
        __hip_atomic_store(&bmg64[g], (ba & 0xffffffffull) | VALIDB,
                           __ATOMIC_RELAXED, __HIP_MEMORY_SCOPE_AGENT);
      if (lane == 32)
        __hip_atomic_store(&bmg64[g + 1], (ba >> 32) | VALIDB,
                           __ATOMIC_RELAXED, __HIP_MEMORY_SCOPE_AGENT);
    }
  }
  __syncthreads();                                // all waves' words issued
  if (t == 0)                                     // conservative hint ordering
    __hip_atomic_store(progress, (unsigned int)(b + 1),
                       __ATOMIC_RELAXED, __HIP_MEMORY_SCOPE_AGENT);

  // ---- outputs (off the chain; block 73's knn overwrites dead scratch) ----
#pragma unroll
  for (int q = 0; q < QRT; ++q)
    if (vq[q]) out[rowq[q]] = kq[q] ? 1 : 0;

#pragma unroll
  for (int q = 0; q < QRT; ++q) {
    if (!vq[q]) continue;
    const int row = rowq[q];
    const int* rp = knn + (long long)row * KNN;
    int* orow = out + M_ROWS + (long long)row * KNN;
    const bool k = kq[q];
#pragma unroll
    for (int u = 0; u < 16; ++u) {
      int4 d = ((const int4*)rp)[u];
      int4 o4;
      o4.x = k ? d.x : M_ROWS;
      o4.y = k ? d.y : M_ROWS;
      o4.z = k ? d.z : M_ROWS;
      o4.w = k ? d.w : M_ROWS;
      ((int4*)orow)[u] = o4;
    }
  }
}

extern "C" void kernel_launch(void* const* d_in, const int* in_sizes, int n_in,
                              void* d_out, int out_size, void* d_ws, size_t ws_size,
                              hipStream_t stream) {
  const int* knn = (const int*)d_in[1];
  int* out = (int*)d_out;
  unsigned int* progress = (unsigned int*)d_ws;

  init_ws_kernel<<<(NBMG + BLK - 1) / BLK, BLK, 0, stream>>>(progress, out);
  nms_chain_kernel<<<NCH, BLK, 0, stream>>>(knn, out, progress);
}

// Round 7
// 470.716 us; speedup vs baseline: 1.0927x; 1.0927x over previous
//
#include <hip/hip_runtime.h>

// Greedy NMS: keep[i] = !any(keep[j] for j in knn[i] if j < i)
//
// Round-19: dissolve the endgame phases into dataflow. R18 refuted the
// P-amortization model (WCH 4->8: predicted H 3.1, measured 6.23): the hop
// time is the ENDGAME's serial phase structure (detect-all -> barrier ->
// copy -> barrier -> probe -> barrier -> fixed-point -> publish), not the
// phase-1 reload. Changes vs R18:
//   - phase-2 wait, lm catch-up copy, and the window-probe stage DELETED.
//   - merged dataflow loop: each thread resolves intra preds via LDS st AND
//     its own window preds (exl entries with j >= pr1lim, carried as an
//     unresolved bitmask) directly against the published global words
//     (per-word in-band valid bits). No block barriers on the chain path.
//   - at steady state only preds in chunk b-1 (~0.87/row) actually spin;
//     older words resolve on the first pass. With per-wave immediate
//     publish, cross-block pipelining happens at wave granularity.
//   - s_sleep(2) only on passes that saw a pending word (R14 LLC lesson).
//   - phase-1 (trigger + lm copy + probe_reload) unchanged — off-turn.
//   - eovf rows (rare): direct full-window rescan vs global words.
// Geometry: R18's (CHUNK=2048, QRT=2, NCH=74, WCH=8, ICAP=6, ECAP=16).
//
// Output encoding (validated round 4): INT32.
//   d_out[0..M)        : kept flags, 1 / 0
//   d_out[M..M+M*64)   : kept_knn, idx or 150000 (tail doubles as u64 word
//                        scratch, owned by block 73 which never publishes)
// d_ws[0..3]: progress counter (zeroed by init kernel each call)

#define M_ROWS 150000
#define KNN    64
#define BLK    1024
#define QRT    2
#define CHUNK  (BLK * QRT)                        // 2048
#define NCH    ((M_ROWS + CHUNK - 1) / CHUNK)     // 74
#define ICAP   6
#define ECAP   16
#define WCH    8                                  // exl window, chunks (16384 rows)
#define W64PC  (CHUNK / 32)                       // 64 published u64 words/chunk
#define LMW    (((NCH - 1) * CHUNK) / 32)         // 4672 u32 mirror words
#define NBMG   ((NCH - 1) * W64PC)                // 4672 published u64 words
#define OUT_INTS (M_ROWS + M_ROWS * KNN)
#define BMG_INT_OFF (OUT_INTS - NBMG * 2)         // 8B-aligned; rows >= 149854
#define VALIDB (1ull << 32)

__global__ void init_ws_kernel(unsigned int* progress, int* out) {
  const int i = blockIdx.x * blockDim.x + threadIdx.x;
  unsigned long long* bmg64 = (unsigned long long*)(out + BMG_INT_OFF);
  if (i < NBMG) bmg64[i] = 0ull;                  // clear stale valid bits
  if (i == 0) *progress = 0u;
}

// reload a row and probe preds j in [lo, hi) against the LDS bitmask
__device__ __forceinline__ bool probe_reload(const int* __restrict__ rp,
                                             const unsigned int* lm,
                                             int lo, int hi) {
  bool s = false;
#pragma unroll
  for (int u = 0; u < 16; ++u) {
    int4 d = ((const int4*)rp)[u];
    int js[4] = {d.x, d.y, d.z, d.w};
#pragma unroll
    for (int m = 0; m < 4; ++m) {
      int j = js[m];
      if (j >= lo && j < hi && ((lm[j >> 5] >> (j & 31)) & 1u)) s = true;
    }
  }
  return s;
}

__global__ __launch_bounds__(BLK) void nms_chain_kernel(
    const int* __restrict__ knn,
    int* __restrict__ out,
    unsigned int* __restrict__ progress)
{
  const int b    = blockIdx.x;
  const int t    = threadIdx.x;
  const int base = b * CHUNK;
  const int winb = (b > WCH) ? (base - WCH * CHUNK) : 0;   // exl window base

  unsigned long long* bmg64 = (unsigned long long*)(out + BMG_INT_OFF);

  __shared__ unsigned char      st[CHUNK];        // 0 unk, 1 kept, 2 supp
  __shared__ unsigned short     il[ICAP][CHUNK];  // TRANSPOSED: conflict-free
  __shared__ unsigned short     exl[ECAP][CHUNK]; // TRANSPOSED: conflict-free
  __shared__ unsigned int       lm[LMW];          // mirrored keep bits
  __shared__ unsigned int       sh_p;

  int  rowq[QRT];
  bool vq[QRT], ovf[QRT], eovf[QRT], supp[QRT];
  int  ic[QRT], ec[QRT];

#pragma unroll
  for (int q = 0; q < QRT; ++q) {
    rowq[q] = base + q * BLK + t;
    vq[q]   = rowq[q] < M_ROWS;
    ic[q] = ec[q] = 0;
    ovf[q] = eovf[q] = supp[q] = false;
  }

  // ---- classification: intra-chunk + static-window pred lists ----
#pragma unroll
  for (int q = 0; q < QRT; ++q) {
    if (!vq[q]) continue;
    const int o   = q * BLK + t;
    const int row = rowq[q];
    const int* rp = knn + (long long)row * KNN;
#pragma unroll
    for (int u = 0; u < 16; ++u) {
      int4 d = ((const int4*)rp)[u];
      int js[4] = {d.x, d.y, d.z, d.w};
#pragma unroll
      for (int m = 0; m < 4; ++m) {
        int j = js[m];
        if (j < row) {                            // strict <: ref semantics
          if (j >= base) {
            if (ic[q] < ICAP) il[ic[q]][o] = (unsigned short)(j - base);
            ++ic[q];
          } else if (j >= winb) {
            if (ec[q] < ECAP) exl[ec[q]][o] = (unsigned short)(j - winb);
            ++ec[q];
          }
          // j < winb: covered by the phase-1 reload probe
        }
      }
    }
  }
#pragma unroll
  for (int q = 0; q < QRT; ++q) {
    ovf[q]  = ic[q] > ICAP; if (ovf[q])  ic[q] = ICAP;
    eovf[q] = ec[q] > ECAP; if (eovf[q]) ec[q] = ECAP;
  }

  // ---- pre-wait: read il lists back into registers (own writes; no barrier;
  //      full unroll -> compile-time indices -> stays in VGPRs) ----
  unsigned short ilr[QRT][ICAP];
#pragma unroll
  for (int q = 0; q < QRT; ++q)
#pragma unroll
    for (int x = 0; x < ICAP; ++x)
      ilr[q][x] = il[x][q * BLK + t];             // garbage beyond ic[q]: never used

  // ---- phase 1 (off-turn): trigger hint, lm copy, deep-pred probe ----
  int praw1 = 0;
  if (b > WCH) {
    if (t < 64) {
      int pr = 0;
      for (int spin = 0; spin < (1 << 22); ++spin) {
        pr = (int)__hip_atomic_load(progress, __ATOMIC_RELAXED,
                                    __HIP_MEMORY_SCOPE_AGENT);
        if (pr >= b - WCH) break;
        __builtin_amdgcn_s_sleep(2);
      }
      if (t == 0) sh_p = (unsigned int)pr;
    }
    __syncthreads();                              // sh_p visible
    praw1 = (int)sh_p; if (praw1 > b) praw1 = b;
    const int wt = praw1 * W64PC;
    for (int w = t; w < wt; w += BLK) {           // per-word valid-spin backstop
      unsigned long long v = __hip_atomic_load(&bmg64[w], __ATOMIC_RELAXED,
                                               __HIP_MEMORY_SCOPE_AGENT);
      int g1 = 0;
      while (!(v & VALIDB) && ++g1 < (1 << 22)) {
        __builtin_amdgcn_s_sleep(1);
        v = __hip_atomic_load(&bmg64[w], __ATOMIC_RELAXED,
                              __HIP_MEMORY_SCOPE_AGENT);
      }
      lm[w] = (unsigned int)v;
    }
    __syncthreads();                              // lm visible
    const int lim = praw1 * CHUNK;
#pragma unroll
    for (int q = 0; q < QRT; ++q)
      if (vq[q])
        supp[q] = probe_reload(knn + (long long)rowq[q] * KNN, lm, 0, lim);
  }
  const int pr1lim = praw1 * CHUNK;

  // ---- build per-thread unresolved ext-pred masks ----
  unsigned int extm[QRT];
  bool eunk[QRT];
#pragma unroll
  for (int q = 0; q < QRT; ++q) {
    extm[q] = 0u; eunk[q] = false;
    if (vq[q] && !supp[q]) {
      const int o = q * BLK + t;
      const int n = ec[q];
#pragma unroll
      for (int x = 0; x < ECAP; ++x) {
        if (x < n) {
          const int j = winb + (int)exl[x][o];
          if (j >= pr1lim) extm[q] |= (1u << x);
        }
      }
      eunk[q] = eovf[q];
    }
  }

  // ---- merged dataflow decision loop (no block barriers on chain path) ----
  unsigned char myst[QRT];
#pragma unroll
  for (int q = 0; q < QRT; ++q) {
    myst[q] = (!vq[q] || supp[q]) ? (unsigned char)2 : (unsigned char)0;
    __hip_atomic_store(&st[q * BLK + t], myst[q],
                       __ATOMIC_RELAXED, __HIP_MEMORY_SCOPE_WORKGROUP);
  }
  __syncthreads();                                // st init visible to all waves

  bool undec = false;
#pragma unroll
  for (int q = 0; q < QRT; ++q) undec |= (myst[q] == 0);

  for (int pass = 0; pass < (1 << 22) && undec; ++pass) {
    bool pend = false;
    undec = false;
#pragma unroll
    for (int q = 0; q < QRT; ++q) {
      if (myst[q] != 0) continue;
      const int o   = q * BLK + t;
      const int row = base + o;
      bool anyK = false, allD = true;
      // intra preds (LDS st)
      if (!ovf[q]) {
#pragma unroll
        for (int x = 0; x < ICAP; ++x) {
          if (x < ic[q]) {
            unsigned char v = __hip_atomic_load(&st[ilr[q][x]],
                __ATOMIC_RELAXED, __HIP_MEMORY_SCOPE_WORKGROUP);
            anyK |= (v == 1); allD &= (v != 0);
          }
        }
      } else {                                    // rare: rescan from global
        const int* rp = knn + (long long)row * KNN;
#pragma unroll
        for (int k = 0; k < KNN; ++k) {
          int j = rp[k];
          if (j >= base && j < row) {
            unsigned char v = __hip_atomic_load(&st[j - base],
                __ATOMIC_RELAXED, __HIP_MEMORY_SCOPE_WORKGROUP);
            anyK |= (v == 1); allD &= (v != 0);
          }
        }
      }
      // ext preds: direct spins on published words (in-band valid bits)
      if (!anyK && extm[q] != 0u) {
        unsigned int m = extm[q];
#pragma unroll
        for (int x = 0; x < ECAP; ++x) {
          if ((m >> x) & 1u) {
            const int j = winb + (int)exl[x][o];
            unsigned long long v = __hip_atomic_load(&bmg64[j >> 5],
                __ATOMIC_RELAXED, __HIP_MEMORY_SCOPE_AGENT);
            if (v & VALIDB) {
              if ((v >> (j & 31)) & 1ull) anyK = true;
              m &= ~(1u << x);
            } else pend = true;
          }
        }
        extm[q] = m;
      }
      if (extm[q] != 0u) allD = false;
      // eovf rows (rare): full-window rescan vs global words
      if (!anyK && eunk[q]) {
        const int lo = (pr1lim > winb) ? pr1lim : winb;
        const int* rp = knn + (long long)row * KNN;
        bool ep = false, ak = false;
#pragma unroll
        for (int k = 0; k < KNN; ++k) {
          int j = rp[k];
          if (j >= lo && j < base) {
            unsigned long long v = __hip_atomic_load(&bmg64[j >> 5],
                __ATOMIC_RELAXED, __HIP_MEMORY_SCOPE_AGENT);
            if (v & VALIDB) { if ((v >> (j & 31)) & 1ull) ak = true; }
            else ep = true;
          }
        }
        if (ak) anyK = true;
        else if (!ep) eunk[q] = false;
        if (ep) pend = true;
      }
      if (eunk[q]) allD = false;

      if (anyK)      myst[q] = 2;
      else if (allD) myst[q] = 1;
      if (myst[q] != 0)
        __hip_atomic_store(&st[o], myst[q],
                           __ATOMIC_RELAXED, __HIP_MEMORY_SCOPE_WORKGROUP);
      else
        undec = true;
    }
    if (pend) __builtin_amdgcn_s_sleep(2);        // throttle LLC polls only
  }

  // ---- publish: PER-WAVE, immediate (wave stores when its lanes decide) ----
  bool kq[QRT];
#pragma unroll
  for (int q = 0; q < QRT; ++q)
    kq[q] = vq[q] && (myst[q] == 1);

  if (b < NCH - 1) {
    const int lane = t & 63;
#pragma unroll
    for (int q = 0; q < QRT; ++q) {
      unsigned long long ba = __ballot(kq[q]);    // rows base+q*1024+(t&~63)+lane
      const int g = b * W64PC + ((q * BLK + (t & ~63)) >> 5);
      if (lane == 0)
        __hip_atomic_store(&bmg64[g], (ba & 0xffffffffull) | VALIDB,
                           __ATOMIC_RELAXED, __HIP_MEMORY_SCOPE_AGENT);
      if (lane == 32)
        __hip_atomic_store(&bmg64[g + 1], (ba >> 32) | VALIDB,
                           __ATOMIC_RELAXED, __HIP_MEMORY_SCOPE_AGENT);
    }
  }
  __syncthreads();                                // all waves' words issued
  if (t == 0)                                     // hint for phase-1 triggers
    __hip_atomic_store(progress, (unsigned int)(b + 1),
                       __ATOMIC_RELAXED, __HIP_MEMORY_SCOPE_AGENT);

  // ---- outputs (off the chain; block 73's knn overwrites dead scratch) ----
#pragma unroll
  for (int q = 0; q < QRT; ++q)
    if (vq[q]) out[rowq[q]] = kq[q] ? 1 : 0;

#pragma unroll
  for (int q = 0; q < QRT; ++q) {
    if (!vq[q]) continue;
    const int row = rowq[q];
    const int* rp = knn + (long long)row * KNN;
    int* orow = out + M_ROWS + (long long)row * KNN;
    const bool k = kq[q];
#pragma unroll
    for (int u = 0; u < 16; ++u) {
      int4 d = ((const int4*)rp)[u];
      int4 o4;
      o4.x = k ? d.x : M_ROWS;
      o4.y = k ? d.y : M_ROWS;
      o4.z = k ? d.z : M_ROWS;
      o4.w = k ? d.w : M_ROWS;
      ((int4*)orow)[u] = o4;
    }
  }
}

extern "C" void kernel_launch(void* const* d_in, const int* in_sizes, int n_in,
                              void* d_out, int out_size, void* d_ws, size_t ws_size,
                              hipStream_t stream) {
  const int* knn = (const int*)d_in[1];
  int* out = (int*)d_out;
  unsigned int* progress = (unsigned int*)d_ws;

  init_ws_kernel<<<(NBMG + BLK - 1) / BLK, BLK, 0, stream>>>(progress, out);
  nms_chain_kernel<<<NCH, BLK, 0, stream>>>(knn, out, progress);
}

// Round 9
// 414.595 us; speedup vs baseline: 1.2406x; 1.1354x over previous
//
#include <hip/hip_runtime.h>

// Greedy NMS: keep[i] = !any(keep[j] for j in knn[i] if j < i)
//
// Round-21: R20 logic verbatim (batched decision-loop polls), with batch
// sizes halved to de-risk VGPR pressure — the one plausible kernel-side
// contributor to R20's double container failure (vv[16]+wv[16] = 64+ VGPRs
// of u64 batches under the 128-VGPR/thread cap of a 1024-thread block ->
// heavy spill). Audit found no hang/fault mechanism: all spins bounded,
// no OOB, uniform barriers.
// Theory under test (from R19's post-mortem): R19 polls each ext pred as
// {branch -> load -> use} => one vmcnt(0) per poll => ~7 SERIAL LLC RTs
// per pass for survivor rows => H ~= 5.3 us/hop is pass-interval-bound.
// Batching all polls before use => ~1-2 RTs per pass.
//   - ext polls: TWO batches of 8 unconditional loads (mask-selected
//     addresses; cleared bits read word 0) -> 2 vmcnt waits per pass.
//   - intra st loads batched (ICAP=6) after the global batch issues.
//   - eovf full-window rescan batched in groups of 8.
//   - s_sleep(1) throttle only on passes that saw a pending word.
// Geometry: CHUNK=2048, QRT=2, NCH=74, WCH=8, ICAP=6, ECAP=16 (R18/R19).
//
// Output encoding (validated round 4): INT32.
//   d_out[0..M)        : kept flags, 1 / 0
//   d_out[M..M+M*64)   : kept_knn, idx or 150000 (tail doubles as u64 word
//                        scratch, owned by block 73 which never publishes)
// d_ws[0..3]: progress counter (zeroed by init kernel each call)

#define M_ROWS 150000
#define KNN    64
#define BLK    1024
#define QRT    2
#define CHUNK  (BLK * QRT)                        // 2048
#define NCH    ((M_ROWS + CHUNK - 1) / CHUNK)     // 74
#define ICAP   6
#define ECAP   16
#define WCH    8                                  // exl window, chunks (16384 rows)
#define W64PC  (CHUNK / 32)                       // 64 published u64 words/chunk
#define LMW    (((NCH - 1) * CHUNK) / 32)         // 4672 u32 mirror words
#define NBMG   ((NCH - 1) * W64PC)                // 4672 published u64 words
#define OUT_INTS (M_ROWS + M_ROWS * KNN)
#define BMG_INT_OFF (OUT_INTS - NBMG * 2)         // 8B-aligned; rows >= 149854
#define VALIDB (1ull << 32)

__global__ void init_ws_kernel(unsigned int* progress, int* out) {
  const int i = blockIdx.x * blockDim.x + threadIdx.x;
  unsigned long long* bmg64 = (unsigned long long*)(out + BMG_INT_OFF);
  if (i < NBMG) bmg64[i] = 0ull;                  // clear stale valid bits
  if (i == 0) *progress = 0u;
}

// reload a row and probe preds j in [lo, hi) against the LDS bitmask
__device__ __forceinline__ bool probe_reload(const int* __restrict__ rp,
                                             const unsigned int* lm,
                                             int lo, int hi) {
  bool s = false;
#pragma unroll
  for (int u = 0; u < 16; ++u) {
    int4 d = ((const int4*)rp)[u];
    int js[4] = {d.x, d.y, d.z, d.w};
#pragma unroll
    for (int m = 0; m < 4; ++m) {
      int j = js[m];
      if (j >= lo && j < hi && ((lm[j >> 5] >> (j & 31)) & 1u)) s = true;
    }
  }
  return s;
}

__global__ __launch_bounds__(BLK) void nms_chain_kernel(
    const int* __restrict__ knn,
    int* __restrict__ out,
    unsigned int* __restrict__ progress)
{
  const int b    = blockIdx.x;
  const int t    = threadIdx.x;
  const int base = b * CHUNK;
  const int winb = (b > WCH) ? (base - WCH * CHUNK) : 0;   // exl window base

  unsigned long long* bmg64 = (unsigned long long*)(out + BMG_INT_OFF);

  __shared__ unsigned char      st[CHUNK];        // 0 unk, 1 kept, 2 supp
  __shared__ unsigned short     il[ICAP][CHUNK];  // TRANSPOSED: conflict-free
  __shared__ unsigned short     exl[ECAP][CHUNK]; // TRANSPOSED: conflict-free
  __shared__ unsigned int       lm[LMW];          // mirrored keep bits
  __shared__ unsigned int       sh_p;

  int  rowq[QRT];
  bool vq[QRT], ovf[QRT], eovf[QRT], supp[QRT];
  int  ic[QRT], ec[QRT];

#pragma unroll
  for (int q = 0; q < QRT; ++q) {
    rowq[q] = base + q * BLK + t;
    vq[q]   = rowq[q] < M_ROWS;
    ic[q] = ec[q] = 0;
    ovf[q] = eovf[q] = supp[q] = false;
  }

  // ---- classification: intra-chunk + static-window pred lists ----
#pragma unroll
  for (int q = 0; q < QRT; ++q) {
    if (!vq[q]) continue;
    const int o   = q * BLK + t;
    const int row = rowq[q];
    const int* rp = knn + (long long)row * KNN;
#pragma unroll
    for (int u = 0; u < 16; ++u) {
      int4 d = ((const int4*)rp)[u];
      int js[4] = {d.x, d.y, d.z, d.w};
#pragma unroll
      for (int m = 0; m < 4; ++m) {
        int j = js[m];
        if (j < row) {                            // strict <: ref semantics
          if (j >= base) {
            if (ic[q] < ICAP) il[ic[q]][o] = (unsigned short)(j - base);
            ++ic[q];
          } else if (j >= winb) {
            if (ec[q] < ECAP) exl[ec[q]][o] = (unsigned short)(j - winb);
            ++ec[q];
          }
          // j < winb: covered by the phase-1 reload probe
        }
      }
    }
  }
#pragma unroll
  for (int q = 0; q < QRT; ++q) {
    ovf[q]  = ic[q] > ICAP; if (ovf[q])  ic[q] = ICAP;
    eovf[q] = ec[q] > ECAP; if (eovf[q]) ec[q] = ECAP;
  }

  // ---- pre-wait: read il lists back into registers (own writes; no barrier;
  //      full unroll -> compile-time indices -> stays in VGPRs) ----
  unsigned short ilr[QRT][ICAP];
#pragma unroll
  for (int q = 0; q < QRT; ++q)
#pragma unroll
    for (int x = 0; x < ICAP; ++x)
      ilr[q][x] = il[x][q * BLK + t];             // garbage beyond ic[q]: never used

  // ---- phase 1 (off-turn): trigger hint, lm copy, deep-pred probe ----
  int praw1 = 0;
  if (b > WCH) {
    if (t < 64) {
      int pr = 0;
      for (int spin = 0; spin < (1 << 22); ++spin) {
        pr = (int)__hip_atomic_load(progress, __ATOMIC_RELAXED,
                                    __HIP_MEMORY_SCOPE_AGENT);
        if (pr >= b - WCH) break;
        __builtin_amdgcn_s_sleep(2);
      }
      if (t == 0) sh_p = (unsigned int)pr;
    }
    __syncthreads();                              // sh_p visible
    praw1 = (int)sh_p; if (praw1 > b) praw1 = b;
    const int wt = praw1 * W64PC;
    for (int w = t; w < wt; w += BLK) {           // per-word valid-spin backstop
      unsigned long long v = __hip_atomic_load(&bmg64[w], __ATOMIC_RELAXED,
                                               __HIP_MEMORY_SCOPE_AGENT);
      int g1 = 0;
      while (!(v & VALIDB) && ++g1 < (1 << 22)) {
        __builtin_amdgcn_s_sleep(1);
        v = __hip_atomic_load(&bmg64[w], __ATOMIC_RELAXED,
                              __HIP_MEMORY_SCOPE_AGENT);
      }
      lm[w] = (unsigned int)v;
    }
    __syncthreads();                              // lm visible
    const int lim = praw1 * CHUNK;
#pragma unroll
    for (int q = 0; q < QRT; ++q)
      if (vq[q])
        supp[q] = probe_reload(knn + (long long)rowq[q] * KNN, lm, 0, lim);
  }
  const int pr1lim = praw1 * CHUNK;

  // ---- build per-thread unresolved ext-pred masks ----
  unsigned int extm[QRT];
  bool eunk[QRT];
#pragma unroll
  for (int q = 0; q < QRT; ++q) {
    extm[q] = 0u; eunk[q] = false;
    if (vq[q] && !supp[q]) {
      const int o = q * BLK + t;
      const int n = ec[q];
#pragma unroll
      for (int x = 0; x < ECAP; ++x) {
        if (x < n) {
          const int j = winb + (int)exl[x][o];
          if (j >= pr1lim) extm[q] |= (1u << x);
        }
      }
      eunk[q] = eovf[q];
    }
  }

  // ---- merged dataflow decision loop (no block barriers on chain path) ----
  unsigned char myst[QRT];
#pragma unroll
  for (int q = 0; q < QRT; ++q) {
    myst[q] = (!vq[q] || supp[q]) ? (unsigned char)2 : (unsigned char)0;
    __hip_atomic_store(&st[q * BLK + t], myst[q],
                       __ATOMIC_RELAXED, __HIP_MEMORY_SCOPE_WORKGROUP);
  }
  __syncthreads();                                // st init visible to all waves

  bool undec = false;
#pragma unroll
  for (int q = 0; q < QRT; ++q) undec |= (myst[q] == 0);

  for (int pass = 0; pass < (1 << 22) && undec; ++pass) {
    bool pend = false;
    undec = false;
#pragma unroll
    for (int q = 0; q < QRT; ++q) {
      if (myst[q] != 0) continue;
      const int o   = q * BLK + t;
      const int row = base + o;
      bool anyK = false, allD = true;
      unsigned int m = extm[q];

      // ---- ext preds: two batches of 8 unconditional loads (mask-selected
      //      addresses; no value-dependent control between loads -> the
      //      compiler batches each group under one vmcnt) ----
      if (m != 0u) {
#pragma unroll
        for (int g = 0; g < 2; ++g) {
          if ((m >> (g * 8)) & 0xffu) {
            unsigned long long vv[8];
#pragma unroll
            for (int x = 0; x < 8; ++x) {
              const int xe = g * 8 + x;
              const int j = winb + (int)exl[xe][o];
              const int w = ((m >> xe) & 1u) ? (j >> 5) : 0;
              vv[x] = __hip_atomic_load(&bmg64[w], __ATOMIC_RELAXED,
                                        __HIP_MEMORY_SCOPE_AGENT);
            }
#pragma unroll
            for (int x = 0; x < 8; ++x) {
              const int xe = g * 8 + x;
              if ((m >> xe) & 1u) {
                const int j = winb + (int)exl[xe][o];
                if (vv[x] & VALIDB) {
                  if ((vv[x] >> (j & 31)) & 1ull) anyK = true;
                  m &= ~(1u << xe);
                } else pend = true;
              }
            }
          }
        }
        extm[q] = m;
      }

      // ---- intra preds: batched LDS loads, then process ----
      if (!ovf[q]) {
        unsigned char vsts[ICAP];
#pragma unroll
        for (int x = 0; x < ICAP; ++x) {
          const int ii = (x < ic[q]) ? (int)ilr[q][x] : 0;
          vsts[x] = __hip_atomic_load(&st[ii],
              __ATOMIC_RELAXED, __HIP_MEMORY_SCOPE_WORKGROUP);
        }
#pragma unroll
        for (int x = 0; x < ICAP; ++x) {
          if (x < ic[q]) { anyK |= (vsts[x] == 1); allD &= (vsts[x] != 0); }
        }
      } else {                                    // ultra-rare: rescan LDS
        const int* rp = knn + (long long)row * KNN;
#pragma unroll
        for (int u = 0; u < 16; ++u) {
          int4 d = ((const int4*)rp)[u];
          int js[4] = {d.x, d.y, d.z, d.w};
          unsigned char sv[4];
#pragma unroll
          for (int m2 = 0; m2 < 4; ++m2) {
            const bool in = (js[m2] >= base && js[m2] < row);
            sv[m2] = __hip_atomic_load(&st[in ? (js[m2] - base) : 0],
                __ATOMIC_RELAXED, __HIP_MEMORY_SCOPE_WORKGROUP);
          }
#pragma unroll
          for (int m2 = 0; m2 < 4; ++m2) {
            if (js[m2] >= base && js[m2] < row) {
              anyK |= (sv[m2] == 1); allD &= (sv[m2] != 0);
            }
          }
        }
      }
      if (extm[q] != 0u) allD = false;

      // ---- eovf rows (rare): batched full-window rescan, groups of 8 ----
      if (!anyK && eunk[q]) {
        const int lo = (pr1lim > winb) ? pr1lim : winb;
        const int* rp = knn + (long long)row * KNN;
        bool ep = false, ak = false;
#pragma unroll
        for (int g = 0; g < 8; ++g) {
          int js[8];
#pragma unroll
          for (int u = 0; u < 2; ++u) {
            int4 d = ((const int4*)rp)[g * 2 + u];
            js[u * 4 + 0] = d.x; js[u * 4 + 1] = d.y;
            js[u * 4 + 2] = d.z; js[u * 4 + 3] = d.w;
          }
          unsigned long long wv[8];
#pragma unroll
          for (int m2 = 0; m2 < 8; ++m2) {
            const bool in = (js[m2] >= lo && js[m2] < base);
            wv[m2] = __hip_atomic_load(&bmg64[in ? (js[m2] >> 5) : 0],
                __ATOMIC_RELAXED, __HIP_MEMORY_SCOPE_AGENT);
          }
#pragma unroll
          for (int m2 = 0; m2 < 8; ++m2) {
            if (js[m2] >= lo && js[m2] < base) {
              if (wv[m2] & VALIDB) { if ((wv[m2] >> (js[m2] & 31)) & 1ull) ak = true; }
              else ep = true;
            }
          }
        }
        if (ak) anyK = true;
        else if (!ep) eunk[q] = false;
        if (ep) pend = true;
      }
      if (eunk[q]) allD = false;

      if (anyK)      myst[q] = 2;
      else if (allD) myst[q] = 1;
      if (myst[q] != 0)
        __hip_atomic_store(&st[o], myst[q],
                           __ATOMIC_RELAXED, __HIP_MEMORY_SCOPE_WORKGROUP);
      else
        undec = true;
    }
    if (pend) __builtin_amdgcn_s_sleep(1);        // throttle LLC polls only
  }

  // ---- publish: PER-WAVE, immediate (wave stores when its lanes decide) ----
  bool kq[QRT];
#pragma unroll
  for (int q = 0; q < QRT; ++q)
    kq[q] = vq[q] && (myst[q] == 1);

  if (b < NCH - 1) {
    const int lane = t & 63;
#pragma unroll
    for (int q = 0; q < QRT; ++q) {
      unsigned long long ba = __ballot(kq[q]);    // rows base+q*1024+(t&~63)+lane
      const int g = b * W64PC + ((q * BLK + (t & ~63)) >> 5);
      if (lane == 0)
        __hip_atomic_store(&bmg64[g], (ba & 0xffffffffull) | VALIDB,
                           __ATOMIC_RELAXED, __HIP_MEMORY_SCOPE_AGENT);
      if (lane == 32)
        __hip_atomic_store(&bmg64[g + 1], (ba >> 32) | VALIDB,
                           __ATOMIC_RELAXED, __HIP_MEMORY_SCOPE_AGENT);
    }
  }
  __syncthreads();                                // all waves' words issued
  if (t == 0)                                     // hint for phase-1 triggers
    __hip_atomic_store(progress, (unsigned int)(b + 1),
                       __ATOMIC_RELAXED, __HIP_MEMORY_SCOPE_AGENT);

  // ---- outputs (off the chain; block 73's knn overwrites dead scratch) ----
#pragma unroll
  for (int q = 0; q < QRT; ++q)
    if (vq[q]) out[rowq[q]] = kq[q] ? 1 : 0;

#pragma unroll
  for (int q = 0; q < QRT; ++q) {
    if (!vq[q]) continue;
    const int row = rowq[q];
    const int* rp = knn + (long long)row * KNN;
    int* orow = out + M_ROWS + (long long)row * KNN;
    const bool k = kq[q];
#pragma unroll
    for (int u = 0; u < 16; ++u) {
      int4 d = ((const int4*)rp)[u];
      int4 o4;
      o4.x = k ? d.x : M_ROWS;
      o4.y = k ? d.y : M_ROWS;
      o4.z = k ? d.z : M_ROWS;
      o4.w = k ? d.w : M_ROWS;
      ((int4*)orow)[u] = o4;
    }
  }
}

extern "C" void kernel_launch(void* const* d_in, const int* in_sizes, int n_in,
                              void* d_out, int out_size, void* d_ws, size_t ws_size,
                              hipStream_t stream) {
  const int* knn = (const int*)d_in[1];
  int* out = (int*)d_out;
  unsigned int* progress = (unsigned int*)d_ws;

  init_ws_kernel<<<(NBMG + BLK - 1) / BLK, BLK, 0, stream>>>(progress, out);
  nms_chain_kernel<<<NCH, BLK, 0, stream>>>(knn, out, progress);
}